// Round 11
// baseline (162.382 us; speedup 1.0000x reference)
//
#include <hip/hip_runtime.h>

#define Df 64
#define NN 10000
#define EE 160000
#define RR 16
#define CC 512
#define CAP1 128
#define CAP2 2048
#define NGEMM 157            // ceil(10000/64) GEMM tiles
#define NAGG 2500            // 10000/4 agg blocks (wave per node)
#define NEDG 625             // 160000/256 edge blocks
#define NSELF 640            // 16 removals * 40 node-blocks
#define ND1B 512             // 16 * (CAP1/4) delta1 blocks
#define ND2B 8192            // 16 * (CAP2/4) delta2 blocks

// ---------------- static device scratch ----------------
__device__ float g_h0[NN * Df];
__device__ float g_h1b[NN * Df];
__device__ float g_h2b[NN * Df];
__device__ float g_agg[NN * Df];
__device__ __align__(16) float g_W20[128 * Df];   // [Ws0;Wn0] row-major [k][d]
__device__ __align__(16) float g_W21[128 * Df];   // [Ws1;Wn1]
__device__ int g_cntI[NN], g_rowI[NN + 1], g_posI[NN], g_csrI[EE];
__device__ int g_mark1[RR][NN], g_mark2[RR][NN];  // 0 = baseline, else slot+1
__device__ int g_n1[RR], g_n2[RR];
__device__ int g_list1[RR][CAP1], g_list2[RR][CAP2];
__device__ float g_d1[RR][CAP1][Df];
__device__ float g_d2[RR][CAP2][Df];
__device__ float g_score[RR * CC];

// ---------------- init: h0 + stacked W + zero cnt/marks ----------------
__global__ void k_init(const float* __restrict__ coords, const float* __restrict__ We,
                       const float* __restrict__ be, const float* __restrict__ Ws0,
                       const float* __restrict__ Wn0, const float* __restrict__ Ws1,
                       const float* __restrict__ Wn1) {
    int i = blockIdx.x * 256 + threadIdx.x;      // grid 2500*256 = 640000
    if (i < NN * Df) {
        int n = i >> 6, d = i & 63;
        g_h0[i] = coords[2 * n] * We[d] + coords[2 * n + 1] * We[Df + d] + be[d];
    }
    if (i < NN) g_cntI[i] = 0;
    if (i < RR * NN) { (&g_mark1[0][0])[i] = 0; (&g_mark2[0][0])[i] = 0; }
    if (i < 8192) {
        int k = i >> 6, d = i & 63;
        g_W20[i] = (k < 64) ? Ws0[k * 64 + d] : Wn0[(k - 64) * 64 + d];
    } else if (i < 16384) {
        int i2 = i - 8192;
        int k = i2 >> 6, d = i2 & 63;
        g_W21[i2] = (k < 64) ? Ws1[k * 64 + d] : Wn1[(k - 64) * 64 + d];
    }
}

// ---------------- CSR build (in-CSR only) ----------------
__global__ void k_hist(const int* __restrict__ dst) {
    int e = blockIdx.x * 256 + threadIdx.x;
    if (e < EE) atomicAdd(&g_cntI[dst[e]], 1);
}

__global__ __launch_bounds__(1024) void k_scan() {    // grid 1
    int t = threadIdx.x;
    int lane = t & 63, wv = t >> 6;
    const int PER = 10;
    int base = t * PER;
    int vals[PER]; int loc = 0;
#pragma unroll
    for (int k = 0; k < PER; k++) { int v = base + k; vals[k] = (v < NN) ? g_cntI[v] : 0; loc += vals[k]; }
    int sc = loc;
#pragma unroll
    for (int off = 1; off < 64; off <<= 1) { int x = __shfl_up(sc, off, 64); if (lane >= off) sc += x; }
    __shared__ int wsum[16];
    if (lane == 63) wsum[wv] = sc;
    __syncthreads();
    if (t < 16) {
        int x = wsum[t]; int s2 = x;
#pragma unroll
        for (int off = 1; off < 16; off <<= 1) { int y = __shfl_up(s2, off, 16); if (t >= off) s2 += y; }
        wsum[t] = s2 - x;
    }
    __syncthreads();
    int run = wsum[wv] + (sc - loc);
#pragma unroll
    for (int k = 0; k < PER; k++) {
        int v = base + k;
        if (v < NN) { g_rowI[v] = run; g_posI[v] = run; run += vals[k]; }
    }
    if (t == 1023) g_rowI[NN] = run;
}

__global__ void k_fill(const int* __restrict__ src, const int* __restrict__ dst) {
    int e = blockIdx.x * 256 + threadIdx.x;
    if (e < EE) {
        int p = atomicAdd(&g_posI[dst[e]], 1);
        g_csrI[p] = src[e];
    }
}

// ---------------- atomic-free compaction (256-thr, 2-pass) ----------------
__device__ __forceinline__ void compact256(int* mark, int* list, int* nout, int cap) {
    int t = threadIdx.x;
    int lane = t & 63, wv = t >> 6;
    const int PER = 40;                          // 256*40 >= NN
    int base = t * PER;
    int loc = 0;
    for (int k = 0; k < PER; k++) { int v = base + k; if (v < NN) loc += mark[v]; }
    int sc = loc;
#pragma unroll
    for (int off = 1; off < 64; off <<= 1) { int x = __shfl_up(sc, off, 64); if (lane >= off) sc += x; }
    __shared__ int wsum[4];
    if (lane == 63) wsum[wv] = sc;
    __syncthreads();
    if (t == 0) { int a = 0; for (int w2 = 0; w2 < 4; w2++) { int x = wsum[w2]; wsum[w2] = a; a += x; } }
    __syncthreads();
    int run = wsum[wv] + (sc - loc);             // exclusive prefix
    for (int k = 0; k < PER; k++) {
        int v = base + k;
        if (v < NN) {
            int f = mark[v];
            if (f && run < cap) { list[run] = v; mark[v] = run + 1; }
            else mark[v] = 0;
            run += f;
        }
    }
    if (t == 255) *nout = (run < cap) ? run : cap;
}

// ---------------- agg (wave per node) ----------------
__device__ __forceinline__ void agg_quad(const float* __restrict__ hin, int b, int tid) {
    int lane = tid & 63, w = tid >> 6;
    int n = b * 4 + w;
    int a0 = g_rowI[n], a1 = g_rowI[n + 1];
    float s = 0.f;
    for (int e = a0; e < a1; e++) s += hin[g_csrI[e] * Df + lane];
    g_agg[n * Df + lane] = s / fmaxf((float)(a1 - a0), 1.f);
}

// ---------------- tiled GEMM body (64 nodes x 64 dims, K=128) ----------------
__device__ __forceinline__ void gemm_tile(const float* __restrict__ hin,
                                          float* __restrict__ hout,
                                          const float* __restrict__ W2,
                                          const float* __restrict__ bias, int m0,
                                          int tid) {
    __shared__ float Xs[32][68];
    __shared__ float Wl[32][64];
    int tx = tid & 15, ty = tid >> 4;
    float acc[4][4];
#pragma unroll
    for (int i = 0; i < 4; i++)
#pragma unroll
        for (int j = 0; j < 4; j++) acc[i][j] = 0.f;

    for (int c = 0; c < 4; c++) {
        const float* src = (c < 2) ? hin : g_agg;
        int kb = (c & 1) * 32;
        int kbase = c * 32;
#pragma unroll
        for (int rep = 0; rep < 2; rep++) {
            int slot = tid + rep * 256;
            int m = slot >> 3, q = slot & 7;
            int n = m0 + m;
            float4 v = make_float4(0.f, 0.f, 0.f, 0.f);
            if (n < NN) v = *(const float4*)&src[n * Df + kb + q * 4];
            Xs[q * 4 + 0][m] = v.x; Xs[q * 4 + 1][m] = v.y;
            Xs[q * 4 + 2][m] = v.z; Xs[q * 4 + 3][m] = v.w;
            int k = slot >> 4, dq = slot & 15;
            *(float4*)&Wl[k][dq * 4] = *(const float4*)&W2[(kbase + k) * Df + dq * 4];
        }
        __syncthreads();
#pragma unroll
        for (int k = 0; k < 32; k++) {
            float4 x4 = *(const float4*)&Xs[k][ty * 4];
            float4 w4 = *(const float4*)&Wl[k][tx * 4];
            float xs[4] = {x4.x, x4.y, x4.z, x4.w};
            float ws[4] = {w4.x, w4.y, w4.z, w4.w};
#pragma unroll
            for (int i = 0; i < 4; i++)
#pragma unroll
                for (int j = 0; j < 4; j++) acc[i][j] += xs[i] * ws[j];
        }
        __syncthreads();
    }
    float4 b4 = *(const float4*)&bias[tx * 4];
    float bb[4] = {b4.x, b4.y, b4.z, b4.w};
#pragma unroll
    for (int i = 0; i < 4; i++) {
        int n = m0 + ty * 4 + i;
        if (n < NN) {
            float4 hv = *(const float4*)&hin[n * Df + tx * 4];
            float4 o;
            o.x = fmaxf(acc[i][0] + bb[0], 0.f) + hv.x;
            o.y = fmaxf(acc[i][1] + bb[1], 0.f) + hv.y;
            o.z = fmaxf(acc[i][2] + bb[2], 0.f) + hv.z;
            o.w = fmaxf(acc[i][3] + bb[3], 0.f) + hv.w;
            *(float4*)&hout[n * Df + tx * 4] = o;
        }
    }
}

// ---------------- L5: agg0 | flag1 | self1 ----------------
__global__ __launch_bounds__(256) void k_s1(const int* __restrict__ removal,
                                            const int* __restrict__ esrc,
                                            const int* __restrict__ edst) {
    int b = blockIdx.x, tid = threadIdx.x;
    if (b < NAGG) { agg_quad(g_h0, b, tid); return; }
    if (b < NAGG + NEDG) {                       // flag1: edges with src == removal[ri]
        int e = (b - NAGG) * 256 + tid;
        if (e < EE) {
            int s = esrc[e], d = edst[e];
#pragma unroll
            for (int ri = 0; ri < RR; ri++)
                if (s == removal[ri]) g_mark1[ri][d] = 1;
        }
        return;
    }
    if (tid < RR) g_mark1[tid][removal[tid]] = 1;    // self1
}

// ---------------- L6: gemm0 | compact1 | flag2-edges | flag2-self ----------------
__global__ __launch_bounds__(256) void k_s2(const float* __restrict__ b0,
                                            const int* __restrict__ esrc,
                                            const int* __restrict__ edst) {
    int b = blockIdx.x, tid = threadIdx.x;
    if (b < NGEMM) { gemm_tile(g_h0, g_h1b, g_W20, b0, b * 64, tid); return; }
    if (b < NGEMM + RR) {
        int ri = b - NGEMM;
        compact256(g_mark1[ri], g_list1[ri], &g_n1[ri], CAP1);
        return;
    }
    if (b < NGEMM + RR + NEDG) {                 // flag2 via edges: src in A1 -> dst
        int e = (b - NGEMM - RR) * 256 + tid;
        if (e < EE) {
            int s = esrc[e], d = edst[e];
#pragma unroll
            for (int ri = 0; ri < RR; ri++)
                if (g_mark1[ri][s] != 0) g_mark2[ri][d] = 1;
        }
        return;
    }
    int rel = b - NGEMM - RR - NEDG;             // flag2 self: A1 subset of A2
    int ri = rel / 40, vb = rel % 40;
    int v = vb * 256 + tid;
    if (v < NN && g_mark1[ri][v] != 0) g_mark2[ri][v] = 1;
}

// ---------------- L7: agg1 | delta1 | compact2 ----------------
__global__ __launch_bounds__(256) void k_s3(const int* __restrict__ removal,
        const float* __restrict__ Ws0, const float* __restrict__ Wn0,
        const float* __restrict__ b0) {
    int b = blockIdx.x, tid = threadIdx.x;
    if (b < NAGG) { agg_quad(g_h1b, b, tid); return; }
    if (b < NAGG + ND1B) {                       // delta1: 4 slots/block (1 per wave)
        __shared__ float s_h[4][Df], s_a[4][Df];
        int rel = b - NAGG;
        int ri = rel >> 5, y = rel & 31;
        int lane = tid & 63, w = tid >> 6;
        int j = y * 4 + w;
        if (j >= g_n1[ri]) return;
        int v = g_list1[ri][j];
        int r = removal[ri];
        float aggd = 0.f; int cnt = 0;
        if (v != r) {
            int s0 = g_rowI[v], s1 = g_rowI[v + 1];
            for (int i = s0; i < s1; i++) {
                int s = g_csrI[i];
                if (s == r) continue;
                aggd += g_h0[s * Df + lane]; cnt++;
            }
        }
        float hv = g_h0[v * Df + lane];
        s_h[w][lane] = hv;
        s_a[w][lane] = aggd / fmaxf((float)cnt, 1.f);
        float acc = b0[lane];
#pragma unroll 16
        for (int k = 0; k < Df; k++)
            acc += s_h[w][k] * Ws0[k * Df + lane] + s_a[w][k] * Wn0[k * Df + lane];
        g_d1[ri][j][lane] = fmaxf(acc, 0.f) + hv;
        return;
    }
    int ri = b - NAGG - ND1B;                    // compact2
    compact256(g_mark2[ri], g_list2[ri], &g_n2[ri], CAP2);
}

// ---------------- L8: gemm1 | delta2 ----------------
__global__ __launch_bounds__(256) void k_s4(const int* __restrict__ removal,
        const float* __restrict__ Ws1, const float* __restrict__ Wn1,
        const float* __restrict__ b1) {
    int b = blockIdx.x, tid = threadIdx.x;
    if (b < NGEMM) { gemm_tile(g_h1b, g_h2b, g_W21, b1, b * 64, tid); return; }
    __shared__ float s_h[4][Df], s_a[4][Df];
    int rel = b - NGEMM;
    int ri = rel >> 9, y = rel & 511;
    int lane = tid & 63, w = tid >> 6;
    int j = y * 4 + w;
    if (j >= g_n2[ri]) return;
    int v = g_list2[ri][j];
    int r = removal[ri];
    const int* mk1 = g_mark1[ri];
    float aggd = 0.f; int cnt = 0;
    if (v != r) {
        int s0 = g_rowI[v], s1 = g_rowI[v + 1];
        for (int i = s0; i < s1; i++) {
            int s = g_csrI[i];
            if (s == r) continue;
            int m = mk1[s];
            const float* hp = (m > 0) ? &g_d1[ri][m - 1][0] : &g_h1b[s * Df];
            aggd += hp[lane]; cnt++;
        }
    }
    int mv = mk1[v];
    float hv = (mv > 0) ? g_d1[ri][mv - 1][lane] : g_h1b[v * Df + lane];
    s_h[w][lane] = hv;
    s_a[w][lane] = aggd / fmaxf((float)cnt, 1.f);
    float acc = b1[lane];
#pragma unroll 16
    for (int k = 0; k < Df; k++)
        acc += s_h[w][k] * Ws1[k * Df + lane] + s_a[w][k] * Wn1[k * Df + lane];
    g_d2[ri][j][lane] = fmaxf(acc, 0.f) + hv;
}

// ---------------- L9: score as GEMM (64 edges x 64 dims per block) ----------------
__global__ __launch_bounds__(256) void k_score(const int* __restrict__ conn,
        const int* __restrict__ removal, const int* __restrict__ esrc,
        const int* __restrict__ edst, const float* __restrict__ We,
        const float* __restrict__ be, const float* __restrict__ Wsc,
        const float* __restrict__ bsc) {
    __shared__ const float* ptrs[128];           // 64 hs rows, 64 hd rows
    __shared__ float Xs[32][68];
    __shared__ float Wl[32][64];
    __shared__ float su;
    int tid = threadIdx.x;
    int e0 = blockIdx.x * 64;
    int ri = e0 >> 9;

    if (tid < 64) {
        int e = conn[e0 + tid];
        int s = esrc[e], d = edst[e];
        int ms = g_mark2[ri][s], md = g_mark2[ri][d];
        ptrs[tid]      = (ms > 0) ? &g_d2[ri][ms - 1][0] : &g_h2b[s * Df];
        ptrs[64 + tid] = (md > 0) ? &g_d2[ri][md - 1][0] : &g_h2b[d * Df];
    } else if (tid < 128) {                      // wave 1: r-embed term
        int lane = tid & 63;
        float up = g_h0[removal[ri] * Df + lane] * Wsc[lane];
#pragma unroll
        for (int off = 32; off > 0; off >>= 1) up += __shfl_xor(up, off, 64);
        if (lane == 0) su = up;
    }
    __syncthreads();

    int tx = tid & 15, ty = tid >> 4;
    float acc[4][4];
#pragma unroll
    for (int i = 0; i < 4; i++)
#pragma unroll
        for (int j = 0; j < 4; j++) acc[i][j] = 0.f;

    for (int c = 0; c < 4; c++) {
        int kb = (c & 1) * 32;
#pragma unroll
        for (int rep = 0; rep < 2; rep++) {
            int slot = tid + rep * 256;
            int m = slot >> 3, q = slot & 7;
            const float* p = ((c < 2) ? ptrs[m] : ptrs[64 + m]) + kb + q * 4;
            float4 v = *(const float4*)p;
            Xs[q * 4 + 0][m] = v.x; Xs[q * 4 + 1][m] = v.y;
            Xs[q * 4 + 2][m] = v.z; Xs[q * 4 + 3][m] = v.w;
            int k = slot >> 4, dq = slot & 15;
            *(float4*)&Wl[k][dq * 4] = *(const float4*)&We[(c * 32 + k) * Df + dq * 4];
        }
        __syncthreads();
#pragma unroll
        for (int k = 0; k < 32; k++) {
            float4 x4 = *(const float4*)&Xs[k][ty * 4];
            float4 w4 = *(const float4*)&Wl[k][tx * 4];
            float xs[4] = {x4.x, x4.y, x4.z, x4.w};
            float ws[4] = {w4.x, w4.y, w4.z, w4.w};
#pragma unroll
            for (int i = 0; i < 4; i++)
#pragma unroll
                for (int j = 0; j < 4; j++) acc[i][j] += xs[i] * ws[j];
        }
        __syncthreads();
    }

    float4 be4 = *(const float4*)&be[tx * 4];
    float4 w2  = *(const float4*)&Wsc[Df + tx * 4];
    float bb[4] = {be4.x, be4.y, be4.z, be4.w};
    float ww[4] = {w2.x, w2.y, w2.z, w2.w};
    float sb = su + bsc[0];
#pragma unroll
    for (int i = 0; i < 4; i++) {
        float part = 0.f;
#pragma unroll
        for (int j = 0; j < 4; j++) part += fmaxf(acc[i][j] + bb[j], 0.f) * ww[j];
#pragma unroll
        for (int off = 1; off < 16; off <<= 1) part += __shfl_xor(part, off, 64);
        if (tx == 0) g_score[e0 + ty * 4 + i] = part + sb;
    }
}

// ---------------- softmax over C per removal ----------------
__global__ void k_softmax(float* __restrict__ out) {
    int r = blockIdx.x;
    int t = threadIdx.x;
    float v0 = g_score[r * CC + t];
    float v1 = g_score[r * CC + 256 + t];
    __shared__ float red[256];
    red[t] = fmaxf(v0, v1);
    __syncthreads();
    for (int off = 128; off > 0; off >>= 1) {
        if (t < off) red[t] = fmaxf(red[t], red[t + off]);
        __syncthreads();
    }
    float mx = red[0];
    __syncthreads();
    float e0 = expf(v0 - mx), e1 = expf(v1 - mx);
    red[t] = e0 + e1;
    __syncthreads();
    for (int off = 128; off > 0; off >>= 1) {
        if (t < off) red[t] += red[t + off];
        __syncthreads();
    }
    float inv = 1.f / red[0];
    out[r * CC + t] = e0 * inv;
    out[r * CC + 256 + t] = e1 * inv;
}

extern "C" void kernel_launch(void* const* d_in, const int* in_sizes, int n_in,
                              void* d_out, int out_size, void* d_ws, size_t ws_size,
                              hipStream_t stream) {
    const float* coords   = (const float*)d_in[0];
    const float* W_emb    = (const float*)d_in[1];
    const float* b_emb    = (const float*)d_in[2];
    const float* W_self0  = (const float*)d_in[3];
    const float* W_neigh0 = (const float*)d_in[4];
    const float* b_gnn0   = (const float*)d_in[5];
    const float* W_self1  = (const float*)d_in[6];
    const float* W_neigh1 = (const float*)d_in[7];
    const float* b_gnn1   = (const float*)d_in[8];
    const float* W_edge   = (const float*)d_in[9];
    const float* b_edge   = (const float*)d_in[10];
    const float* W_score  = (const float*)d_in[11];
    const float* b_score  = (const float*)d_in[12];
    const int* esrc       = (const int*)d_in[13];
    const int* edst       = (const int*)d_in[14];
    const int* removal    = (const int*)d_in[15];
    const int* conn       = (const int*)d_in[16];

    k_init<<<2500, 256, 0, stream>>>(coords, W_emb, b_emb, W_self0, W_neigh0,
                                     W_self1, W_neigh1);
    k_hist<<<NEDG, 256, 0, stream>>>(edst);
    k_scan<<<1, 1024, 0, stream>>>();
    k_fill<<<NEDG, 256, 0, stream>>>(esrc, edst);

    k_s1<<<NAGG + NEDG + 1, 256, 0, stream>>>(removal, esrc, edst);
    k_s2<<<NGEMM + RR + NEDG + NSELF, 256, 0, stream>>>(b_gnn0, esrc, edst);
    k_s3<<<NAGG + ND1B + RR, 256, 0, stream>>>(removal, W_self0, W_neigh0, b_gnn0);
    k_s4<<<NGEMM + ND2B, 256, 0, stream>>>(removal, W_self1, W_neigh1, b_gnn1);

    k_score<<<RR * CC / 64, 256, 0, stream>>>(conn, removal, esrc, edst,
                                              W_edge, b_edge, W_score, b_score);
    k_softmax<<<RR, 256, 0, stream>>>((float*)d_out);
}

// Round 12
// 132.832 us; speedup vs baseline: 1.2225x; 1.2225x over previous
//
#include <hip/hip_runtime.h>

#define Df 64
#define NN 10000
#define EE 160000
#define RR 16
#define CC 512
#define CAP1 128
#define CAP2 2048
#define NGEMM 157            // ceil(10000/64) GEMM tiles
#define NAGG 2500            // 10000/4 agg blocks (wave per node)
#define NEDG 625             // 160000/256 edge blocks
#define NSLF 40              // ceil(10000/256) self-merge blocks
#define ND1B 512             // 16 * (CAP1/4) delta1 blocks
#define ND2B 8192            // 16 * (CAP2/4) delta2 blocks

// ---------------- static device scratch ----------------
__device__ float g_h0[NN * Df];
__device__ float g_h1b[NN * Df];
__device__ float g_h2b[NN * Df];
__device__ float g_agg[NN * Df];
__device__ float g_zrow[Df];                      // zeros
__device__ __align__(16) float g_W20[128 * Df];   // [Ws0;Wn0] row-major [k][d]
__device__ __align__(16) float g_W21[128 * Df];   // [Ws1;Wn1]
__device__ int g_cntI[NN], g_rowI[NN + 1], g_posI[NN], g_csrI[EE];
__device__ int g_m1mask[NN], g_m2mask[NN];        // bit ri = member of A1/A2 for removal ri
__device__ int g_mark1[RR][NN], g_mark2[RR][NN];  // slot+1 maps (fully rewritten each call)
__device__ int g_n1[RR], g_n2[RR];
__device__ int g_list1[RR][CAP1], g_list2[RR][CAP2];
__device__ float g_d1[RR][CAP1][Df];
__device__ float g_d2[RR][CAP2][Df];
__device__ float g_score[RR * CC];

// ---------------- init: h0 + stacked W + zero cnt/masks/zrow ----------------
__global__ void k_init(const float* __restrict__ coords, const float* __restrict__ We,
                       const float* __restrict__ be, const float* __restrict__ Ws0,
                       const float* __restrict__ Wn0, const float* __restrict__ Ws1,
                       const float* __restrict__ Wn1) {
    int i = blockIdx.x * 256 + threadIdx.x;
    if (i < NN * Df) {
        int n = i >> 6, d = i & 63;
        g_h0[i] = coords[2 * n] * We[d] + coords[2 * n + 1] * We[Df + d] + be[d];
    }
    if (i < NN) { g_cntI[i] = 0; g_m1mask[i] = 0; g_m2mask[i] = 0; }
    if (i < Df) g_zrow[i] = 0.f;
    if (i < 8192) {
        int k = i >> 6, d = i & 63;
        g_W20[i] = (k < 64) ? Ws0[k * 64 + d] : Wn0[(k - 64) * 64 + d];
    } else if (i < 16384) {
        int i2 = i - 8192;
        int k = i2 >> 6, d = i2 & 63;
        g_W21[i2] = (k < 64) ? Ws1[k * 64 + d] : Wn1[(k - 64) * 64 + d];
    }
}

// ---------------- CSR build (in-CSR only) ----------------
__global__ void k_hist(const int* __restrict__ dst) {
    int e = blockIdx.x * 256 + threadIdx.x;
    if (e < EE) atomicAdd(&g_cntI[dst[e]], 1);
}

__global__ __launch_bounds__(1024) void k_scan() {    // grid 1
    int t = threadIdx.x;
    int lane = t & 63, wv = t >> 6;
    const int PER = 10;
    int base = t * PER;
    int vals[PER]; int loc = 0;
#pragma unroll
    for (int k = 0; k < PER; k++) { int v = base + k; vals[k] = (v < NN) ? g_cntI[v] : 0; loc += vals[k]; }
    int sc = loc;
#pragma unroll
    for (int off = 1; off < 64; off <<= 1) { int x = __shfl_up(sc, off, 64); if (lane >= off) sc += x; }
    __shared__ int wsum[16];
    if (lane == 63) wsum[wv] = sc;
    __syncthreads();
    if (t < 16) {
        int x = wsum[t]; int s2 = x;
#pragma unroll
        for (int off = 1; off < 16; off <<= 1) { int y = __shfl_up(s2, off, 16); if (t >= off) s2 += y; }
        wsum[t] = s2 - x;
    }
    __syncthreads();
    int run = wsum[wv] + (sc - loc);
#pragma unroll
    for (int k = 0; k < PER; k++) {
        int v = base + k;
        if (v < NN) { g_rowI[v] = run; g_posI[v] = run; run += vals[k]; }
    }
    if (t == 1023) g_rowI[NN] = run;
}

__global__ void k_fill(const int* __restrict__ src, const int* __restrict__ dst) {
    int e = blockIdx.x * 256 + threadIdx.x;
    if (e < EE) {
        int p = atomicAdd(&g_posI[dst[e]], 1);
        g_csrI[p] = src[e];
    }
}

// ---------------- mask-bit compaction (256-thr, 2-pass, atomic-free) ----------------
__device__ __forceinline__ void compact256(const int* __restrict__ maskArr, int bit,
                                           int* mark, int* list, int* nout, int cap) {
    int t = threadIdx.x;
    int lane = t & 63, wv = t >> 6;
    const int PER = 40;                          // 256*40 >= NN
    int base = t * PER;
    int loc = 0;
    for (int k = 0; k < PER; k++) { int v = base + k; if (v < NN) loc += (maskArr[v] >> bit) & 1; }
    int sc = loc;
#pragma unroll
    for (int off = 1; off < 64; off <<= 1) { int x = __shfl_up(sc, off, 64); if (lane >= off) sc += x; }
    __shared__ int wsum[4];
    if (lane == 63) wsum[wv] = sc;
    __syncthreads();
    if (t == 0) { int a = 0; for (int w2 = 0; w2 < 4; w2++) { int x = wsum[w2]; wsum[w2] = a; a += x; } }
    __syncthreads();
    int run = wsum[wv] + (sc - loc);             // exclusive prefix
    for (int k = 0; k < PER; k++) {
        int v = base + k;
        if (v < NN) {
            int f = (maskArr[v] >> bit) & 1;
            if (f && run < cap) { list[run] = v; mark[v] = run + 1; }
            else mark[v] = 0;
            run += f;
        }
    }
    if (t == 255) *nout = (run < cap) ? run : cap;
}

// ---------------- agg (wave per node, 4x unrolled gather) ----------------
__device__ __forceinline__ void agg_quad(const float* __restrict__ hin, int b, int tid) {
    int lane = tid & 63, w = tid >> 6;
    int n = b * 4 + w;
    int a0 = g_rowI[n], a1 = g_rowI[n + 1];
    float s0 = 0.f, s1 = 0.f, s2 = 0.f, s3 = 0.f;
    int i = a0;
    for (; i + 4 <= a1; i += 4) {
        int c0 = g_csrI[i], c1 = g_csrI[i + 1], c2 = g_csrI[i + 2], c3 = g_csrI[i + 3];
        s0 += hin[c0 * Df + lane];
        s1 += hin[c1 * Df + lane];
        s2 += hin[c2 * Df + lane];
        s3 += hin[c3 * Df + lane];
    }
    for (; i < a1; i++) s0 += hin[g_csrI[i] * Df + lane];
    float s = (s0 + s1) + (s2 + s3);
    g_agg[n * Df + lane] = s / fmaxf((float)(a1 - a0), 1.f);
}

// ---------------- tiled GEMM body (64 nodes x 64 dims, K=128) ----------------
__device__ __forceinline__ void gemm_tile(const float* __restrict__ hin,
                                          float* __restrict__ hout,
                                          const float* __restrict__ W2,
                                          const float* __restrict__ bias, int m0,
                                          int tid) {
    __shared__ float Xs[32][68];
    __shared__ float Wl[32][64];
    int tx = tid & 15, ty = tid >> 4;
    float acc[4][4];
#pragma unroll
    for (int i = 0; i < 4; i++)
#pragma unroll
        for (int j = 0; j < 4; j++) acc[i][j] = 0.f;

    for (int c = 0; c < 4; c++) {
        const float* src = (c < 2) ? hin : g_agg;
        int kb = (c & 1) * 32;
        int kbase = c * 32;
#pragma unroll
        for (int rep = 0; rep < 2; rep++) {
            int slot = tid + rep * 256;
            int m = slot >> 3, q = slot & 7;
            int n = m0 + m;
            float4 v = make_float4(0.f, 0.f, 0.f, 0.f);
            if (n < NN) v = *(const float4*)&src[n * Df + kb + q * 4];
            Xs[q * 4 + 0][m] = v.x; Xs[q * 4 + 1][m] = v.y;
            Xs[q * 4 + 2][m] = v.z; Xs[q * 4 + 3][m] = v.w;
            int k = slot >> 4, dq = slot & 15;
            *(float4*)&Wl[k][dq * 4] = *(const float4*)&W2[(kbase + k) * Df + dq * 4];
        }
        __syncthreads();
#pragma unroll
        for (int k = 0; k < 32; k++) {
            float4 x4 = *(const float4*)&Xs[k][ty * 4];
            float4 w4 = *(const float4*)&Wl[k][tx * 4];
            float xs[4] = {x4.x, x4.y, x4.z, x4.w};
            float ws[4] = {w4.x, w4.y, w4.z, w4.w};
#pragma unroll
            for (int i = 0; i < 4; i++)
#pragma unroll
                for (int j = 0; j < 4; j++) acc[i][j] += xs[i] * ws[j];
        }
        __syncthreads();
    }
    float4 b4 = *(const float4*)&bias[tx * 4];
    float bb[4] = {b4.x, b4.y, b4.z, b4.w};
#pragma unroll
    for (int i = 0; i < 4; i++) {
        int n = m0 + ty * 4 + i;
        if (n < NN) {
            float4 hv = *(const float4*)&hin[n * Df + tx * 4];
            float4 o;
            o.x = fmaxf(acc[i][0] + bb[0], 0.f) + hv.x;
            o.y = fmaxf(acc[i][1] + bb[1], 0.f) + hv.y;
            o.z = fmaxf(acc[i][2] + bb[2], 0.f) + hv.z;
            o.w = fmaxf(acc[i][3] + bb[3], 0.f) + hv.w;
            *(float4*)&hout[n * Df + tx * 4] = o;
        }
    }
}

// ---------------- L5: agg0 | flag1(mask) | self1 ----------------
__global__ __launch_bounds__(256) void k_s1(const int* __restrict__ removal,
                                            const int* __restrict__ esrc,
                                            const int* __restrict__ edst) {
    int b = blockIdx.x, tid = threadIdx.x;
    if (b < NAGG) { agg_quad(g_h0, b, tid); return; }
    if (b < NAGG + NEDG) {                       // flag1: edges with src == removal[ri]
        int e = (b - NAGG) * 256 + tid;
        if (e < EE) {
            int s = esrc[e], d = edst[e];
            int m = 0;
#pragma unroll
            for (int ri = 0; ri < RR; ri++)
                if (s == removal[ri]) m |= (1 << ri);
            if (m) atomicOr(&g_m1mask[d], m);
        }
        return;
    }
    if (tid < RR) atomicOr(&g_m1mask[removal[tid]], 1 << tid);   // self1
}

// ---------------- L6: gemm0 | compact1 | flag2-edges | flag2-self ----------------
__global__ __launch_bounds__(256) void k_s2(const float* __restrict__ b0,
                                            const int* __restrict__ esrc,
                                            const int* __restrict__ edst) {
    int b = blockIdx.x, tid = threadIdx.x;
    if (b < NGEMM) { gemm_tile(g_h0, g_h1b, g_W20, b0, b * 64, tid); return; }
    if (b < NGEMM + RR) {
        int ri = b - NGEMM;
        compact256(g_m1mask, ri, g_mark1[ri], g_list1[ri], &g_n1[ri], CAP1);
        return;
    }
    if (b < NGEMM + RR + NEDG) {                 // flag2 via edges: one mask load per edge
        int e = (b - NGEMM - RR) * 256 + tid;
        if (e < EE) {
            int m = g_m1mask[esrc[e]];
            if (m) atomicOr(&g_m2mask[edst[e]], m);
        }
        return;
    }
    int v = (b - NGEMM - RR - NEDG) * 256 + tid; // flag2 self: A1 subset of A2
    if (v < NN) {
        int m = g_m1mask[v];
        if (m) atomicOr(&g_m2mask[v], m);
    }
}

// ---------------- L7: agg1 | delta1 | compact2 ----------------
__global__ __launch_bounds__(256) void k_s3(const int* __restrict__ removal,
        const float* __restrict__ Ws0, const float* __restrict__ Wn0,
        const float* __restrict__ b0) {
    int b = blockIdx.x, tid = threadIdx.x;
    if (b < NAGG) { agg_quad(g_h1b, b, tid); return; }
    if (b < NAGG + ND1B) {                       // delta1: 4 slots/block (1 per wave)
        __shared__ float s_h[4][Df], s_a[4][Df];
        int rel = b - NAGG;
        int ri = rel >> 5, y = rel & 31;
        int lane = tid & 63, w = tid >> 6;
        int j = y * 4 + w;
        if (j >= g_n1[ri]) return;
        int v = g_list1[ri][j];
        int r = removal[ri];
        float p0s = 0.f, p1s = 0.f, p2s = 0.f, p3s = 0.f; int cnt = 0;
        if (v != r) {
            int e0 = g_rowI[v], e1 = g_rowI[v + 1];
            int i = e0;
            for (; i + 4 <= e1; i += 4) {
                int c0 = g_csrI[i], c1 = g_csrI[i + 1], c2 = g_csrI[i + 2], c3 = g_csrI[i + 3];
                const float* p0 = (c0 == r) ? g_zrow : &g_h0[c0 * Df];
                const float* p1 = (c1 == r) ? g_zrow : &g_h0[c1 * Df];
                const float* p2 = (c2 == r) ? g_zrow : &g_h0[c2 * Df];
                const float* p3 = (c3 == r) ? g_zrow : &g_h0[c3 * Df];
                p0s += p0[lane]; p1s += p1[lane]; p2s += p2[lane]; p3s += p3[lane];
                cnt += (c0 != r) + (c1 != r) + (c2 != r) + (c3 != r);
            }
            for (; i < e1; i++) {
                int c = g_csrI[i];
                const float* p = (c == r) ? g_zrow : &g_h0[c * Df];
                p0s += p[lane]; cnt += (c != r);
            }
        }
        float aggd = (p0s + p1s) + (p2s + p3s);
        float hv = g_h0[v * Df + lane];
        s_h[w][lane] = hv;
        s_a[w][lane] = aggd / fmaxf((float)cnt, 1.f);
        float acc = b0[lane];
#pragma unroll 16
        for (int k = 0; k < Df; k++)
            acc += s_h[w][k] * Ws0[k * Df + lane] + s_a[w][k] * Wn0[k * Df + lane];
        g_d1[ri][j][lane] = fmaxf(acc, 0.f) + hv;
        return;
    }
    int ri = b - NAGG - ND1B;                    // compact2
    compact256(g_m2mask, ri, g_mark2[ri], g_list2[ri], &g_n2[ri], CAP2);
}

// ---------------- L8: gemm1 | delta2 ----------------
__global__ __launch_bounds__(256) void k_s4(const int* __restrict__ removal,
        const float* __restrict__ Ws1, const float* __restrict__ Wn1,
        const float* __restrict__ b1) {
    int b = blockIdx.x, tid = threadIdx.x;
    if (b < NGEMM) { gemm_tile(g_h1b, g_h2b, g_W21, b1, b * 64, tid); return; }
    __shared__ float s_h[4][Df], s_a[4][Df];
    int rel = b - NGEMM;
    int ri = rel >> 9, y = rel & 511;
    int lane = tid & 63, w = tid >> 6;
    int j = y * 4 + w;
    if (j >= g_n2[ri]) return;
    int v = g_list2[ri][j];
    int r = removal[ri];
    const int* mk1 = g_mark1[ri];
    float p0s = 0.f, p1s = 0.f, p2s = 0.f, p3s = 0.f; int cnt = 0;
    if (v != r) {
        int e0 = g_rowI[v], e1 = g_rowI[v + 1];
        int i = e0;
        for (; i + 4 <= e1; i += 4) {
            int c0 = g_csrI[i], c1 = g_csrI[i + 1], c2 = g_csrI[i + 2], c3 = g_csrI[i + 3];
            int m0 = mk1[c0], m1 = mk1[c1], m2 = mk1[c2], m3 = mk1[c3];
            const float* p0 = (c0 == r) ? g_zrow : (m0 > 0 ? &g_d1[ri][m0 - 1][0] : &g_h1b[c0 * Df]);
            const float* p1 = (c1 == r) ? g_zrow : (m1 > 0 ? &g_d1[ri][m1 - 1][0] : &g_h1b[c1 * Df]);
            const float* p2 = (c2 == r) ? g_zrow : (m2 > 0 ? &g_d1[ri][m2 - 1][0] : &g_h1b[c2 * Df]);
            const float* p3 = (c3 == r) ? g_zrow : (m3 > 0 ? &g_d1[ri][m3 - 1][0] : &g_h1b[c3 * Df]);
            p0s += p0[lane]; p1s += p1[lane]; p2s += p2[lane]; p3s += p3[lane];
            cnt += (c0 != r) + (c1 != r) + (c2 != r) + (c3 != r);
        }
        for (; i < e1; i++) {
            int c = g_csrI[i];
            int m = mk1[c];
            const float* p = (c == r) ? g_zrow : (m > 0 ? &g_d1[ri][m - 1][0] : &g_h1b[c * Df]);
            p0s += p[lane]; cnt += (c != r);
        }
    }
    float aggd = (p0s + p1s) + (p2s + p3s);
    int mv = mk1[v];
    float hv = (mv > 0) ? g_d1[ri][mv - 1][lane] : g_h1b[v * Df + lane];
    s_h[w][lane] = hv;
    s_a[w][lane] = aggd / fmaxf((float)cnt, 1.f);
    float acc = b1[lane];
#pragma unroll 16
    for (int k = 0; k < Df; k++)
        acc += s_h[w][k] * Ws1[k * Df + lane] + s_a[w][k] * Wn1[k * Df + lane];
    g_d2[ri][j][lane] = fmaxf(acc, 0.f) + hv;
}

// ---------------- L9: score as GEMM (64 edges x 64 dims per block) ----------------
__global__ __launch_bounds__(256) void k_score(const int* __restrict__ conn,
        const int* __restrict__ removal, const int* __restrict__ esrc,
        const int* __restrict__ edst, const float* __restrict__ We,
        const float* __restrict__ be, const float* __restrict__ Wsc,
        const float* __restrict__ bsc) {
    __shared__ const float* ptrs[128];           // 64 hs rows, 64 hd rows
    __shared__ float Xs[32][68];
    __shared__ float Wl[32][64];
    __shared__ float su;
    int tid = threadIdx.x;
    int e0 = blockIdx.x * 64;
    int ri = e0 >> 9;

    if (tid < 64) {
        int e = conn[e0 + tid];
        int s = esrc[e], d = edst[e];
        int ms = g_mark2[ri][s], md = g_mark2[ri][d];
        ptrs[tid]      = (ms > 0) ? &g_d2[ri][ms - 1][0] : &g_h2b[s * Df];
        ptrs[64 + tid] = (md > 0) ? &g_d2[ri][md - 1][0] : &g_h2b[d * Df];
    } else if (tid < 128) {                      // wave 1: r-embed term
        int lane = tid & 63;
        float up = g_h0[removal[ri] * Df + lane] * Wsc[lane];
#pragma unroll
        for (int off = 32; off > 0; off >>= 1) up += __shfl_xor(up, off, 64);
        if (lane == 0) su = up;
    }
    __syncthreads();

    int tx = tid & 15, ty = tid >> 4;
    float acc[4][4];
#pragma unroll
    for (int i = 0; i < 4; i++)
#pragma unroll
        for (int j = 0; j < 4; j++) acc[i][j] = 0.f;

    for (int c = 0; c < 4; c++) {
        int kb = (c & 1) * 32;
#pragma unroll
        for (int rep = 0; rep < 2; rep++) {
            int slot = tid + rep * 256;
            int m = slot >> 3, q = slot & 7;
            const float* p = ((c < 2) ? ptrs[m] : ptrs[64 + m]) + kb + q * 4;
            float4 v = *(const float4*)p;
            Xs[q * 4 + 0][m] = v.x; Xs[q * 4 + 1][m] = v.y;
            Xs[q * 4 + 2][m] = v.z; Xs[q * 4 + 3][m] = v.w;
            int k = slot >> 4, dq = slot & 15;
            *(float4*)&Wl[k][dq * 4] = *(const float4*)&We[(c * 32 + k) * Df + dq * 4];
        }
        __syncthreads();
#pragma unroll
        for (int k = 0; k < 32; k++) {
            float4 x4 = *(const float4*)&Xs[k][ty * 4];
            float4 w4 = *(const float4*)&Wl[k][tx * 4];
            float xs[4] = {x4.x, x4.y, x4.z, x4.w};
            float ws[4] = {w4.x, w4.y, w4.z, w4.w};
#pragma unroll
            for (int i = 0; i < 4; i++)
#pragma unroll
                for (int j = 0; j < 4; j++) acc[i][j] += xs[i] * ws[j];
        }
        __syncthreads();
    }

    float4 be4 = *(const float4*)&be[tx * 4];
    float4 w2  = *(const float4*)&Wsc[Df + tx * 4];
    float bb[4] = {be4.x, be4.y, be4.z, be4.w};
    float ww[4] = {w2.x, w2.y, w2.z, w2.w};
    float sb = su + bsc[0];
#pragma unroll
    for (int i = 0; i < 4; i++) {
        float part = 0.f;
#pragma unroll
        for (int j = 0; j < 4; j++) part += fmaxf(acc[i][j] + bb[j], 0.f) * ww[j];
#pragma unroll
        for (int off = 1; off < 16; off <<= 1) part += __shfl_xor(part, off, 64);
        if (tx == 0) g_score[e0 + ty * 4 + i] = part + sb;
    }
}

// ---------------- softmax over C per removal ----------------
__global__ void k_softmax(float* __restrict__ out) {
    int r = blockIdx.x;
    int t = threadIdx.x;
    float v0 = g_score[r * CC + t];
    float v1 = g_score[r * CC + 256 + t];
    __shared__ float red[256];
    red[t] = fmaxf(v0, v1);
    __syncthreads();
    for (int off = 128; off > 0; off >>= 1) {
        if (t < off) red[t] = fmaxf(red[t], red[t + off]);
        __syncthreads();
    }
    float mx = red[0];
    __syncthreads();
    float e0 = expf(v0 - mx), e1 = expf(v1 - mx);
    red[t] = e0 + e1;
    __syncthreads();
    for (int off = 128; off > 0; off >>= 1) {
        if (t < off) red[t] += red[t + off];
        __syncthreads();
    }
    float inv = 1.f / red[0];
    out[r * CC + t] = e0 * inv;
    out[r * CC + 256 + t] = e1 * inv;
}

extern "C" void kernel_launch(void* const* d_in, const int* in_sizes, int n_in,
                              void* d_out, int out_size, void* d_ws, size_t ws_size,
                              hipStream_t stream) {
    const float* coords   = (const float*)d_in[0];
    const float* W_emb    = (const float*)d_in[1];
    const float* b_emb    = (const float*)d_in[2];
    const float* W_self0  = (const float*)d_in[3];
    const float* W_neigh0 = (const float*)d_in[4];
    const float* b_gnn0   = (const float*)d_in[5];
    const float* W_self1  = (const float*)d_in[6];
    const float* W_neigh1 = (const float*)d_in[7];
    const float* b_gnn1   = (const float*)d_in[8];
    const float* W_edge   = (const float*)d_in[9];
    const float* b_edge   = (const float*)d_in[10];
    const float* W_score  = (const float*)d_in[11];
    const float* b_score  = (const float*)d_in[12];
    const int* esrc       = (const int*)d_in[13];
    const int* edst       = (const int*)d_in[14];
    const int* removal    = (const int*)d_in[15];
    const int* conn       = (const int*)d_in[16];

    k_init<<<2500, 256, 0, stream>>>(coords, W_emb, b_emb, W_self0, W_neigh0,
                                     W_self1, W_neigh1);
    k_hist<<<NEDG, 256, 0, stream>>>(edst);
    k_scan<<<1, 1024, 0, stream>>>();
    k_fill<<<NEDG, 256, 0, stream>>>(esrc, edst);

    k_s1<<<NAGG + NEDG + 1, 256, 0, stream>>>(removal, esrc, edst);
    k_s2<<<NGEMM + RR + NEDG + NSLF, 256, 0, stream>>>(b_gnn0, esrc, edst);
    k_s3<<<NAGG + ND1B + RR, 256, 0, stream>>>(removal, W_self0, W_neigh0, b_gnn0);
    k_s4<<<NGEMM + ND2B, 256, 0, stream>>>(removal, W_self1, W_neigh1, b_gnn1);

    k_score<<<RR * CC / 64, 256, 0, stream>>>(conn, removal, esrc, edst,
                                              W_edge, b_edge, W_score, b_score);
    k_softmax<<<RR, 256, 0, stream>>>((float*)d_out);
}